// Round 1
// baseline (2433.531 us; speedup 1.0000x reference)
//
#include <hip/hip_runtime.h>
#include <hip/hip_bf16.h>
#include <stdint.h>
#include <string.h>

// ---------------- problem constants ----------------
// B=64, T=256, D=H=256, L=50, O=2; K = 2H = 512 (concat [h_in; h_prev]); G = 4H = 1024
#define NB   64
#define NT   256
#define NH   256
#define NL   50
#define NK   512
#define NG   1024

typedef __attribute__((ext_vector_type(8)))  short   short8;
typedef __attribute__((ext_vector_type(8)))  __bf16  bf16x8;
typedef __attribute__((ext_vector_type(4)))  float   float4v;
typedef __attribute__((ext_vector_type(4)))  int     int4v;

__device__ __forceinline__ unsigned short f2bf(float f) {
  union { float f; uint32_t u; } v; v.f = f;
  uint32_t u = v.u;
  uint32_t r = (u + 0x7FFFu + ((u >> 16) & 1u)) >> 16;   // RNE
  return (unsigned short)r;
}
__device__ __forceinline__ float bf2f(unsigned short s) {
  union { uint32_t u; float f; } v; v.u = ((uint32_t)s) << 16;
  return v.f;
}
// fast, overflow-safe activations (tolerance 1e-2; v_exp/v_rcp ~1ulp)
__device__ __forceinline__ float sigmoid_f(float x) {
  return 1.0f / (1.0f + __expf(-x));
}
__device__ __forceinline__ float tanh_f(float x) {
  float e = __expf(-2.0f * __builtin_fabsf(x));   // in (0,1]
  float r = (1.0f - e) / (1.0f + e);
  return __builtin_copysignf(r, x);
}

// ---- coherent, COALESCED 16B ops (sc1 = agent scope, LLC-direct; same
// coherence point the validated 8B atomics used, but wave-coalescable) ----
__device__ __forceinline__ short8 ldg_sc1_b128(const unsigned short* p) {
  short8 r;
  asm volatile("global_load_dwordx4 %0, %1, off sc1" : "=v"(r) : "v"(p) : "memory");
  return r;
}
__device__ __forceinline__ void stg_sc1_b128(unsigned short* p, short8 v) {
  asm volatile("global_store_dwordx4 %0, %1, off sc1" :: "v"(p), "v"(v) : "memory");
}
__device__ __forceinline__ void wait_vm0() {
  asm volatile("s_waitcnt vmcnt(0)" ::: "memory");
}
// poll 4 per-WG flags with ONE 16B coherent load (all lanes same addr -> 1 txn)
__device__ __forceinline__ void wave_wait_all4(const int* p) {
  for (;;) {
    int4v f;
    asm volatile("global_load_dwordx4 %0, %1, off sc1\n\ts_waitcnt vmcnt(0)"
                 : "=v"(f) : "v"(p) : "memory");
    if ((f[0] & f[1] & f[2] & f[3]) != 0) break;
  }
}

// ---------------- workspace layout (bytes) ----------------
#define OFF_WSWZ  0
#define OFF_BIAS  52428800
#define OFF_XBF   52633600
#define OFF_HRING 61022208
#define OFF_Y     67575808
#define OFF_PROD  75964416
#define OFF_CONS  76169216
// total: 76,374,016 bytes  (prod4/cons4: 50*256*4 ints = 204,800 B each)

// ---------------- preprocessing ----------------
// Weight swizzle: Wswz[idx], idx = ((((l*16+c)*4+q)*16+kt)*64+lam)*8+j
// holds Wcat[g = q*256 + c*16 + (lam&15)][k = kt*32 + (lam>>4)*8 + j] as bf16.
// Exact MFMA B-fragment lane order (verified R1-R6).
__global__ void prep_w(const float* __restrict__ Wih, const float* __restrict__ Whh,
                       unsigned short* __restrict__ Wswz) {
  int idx = blockIdx.x * 256 + threadIdx.x;        // 26,214,400 total
  int j   = idx & 7;
  int lam = (idx >> 3) & 63;
  int kt  = (idx >> 9) & 15;
  int q   = (idx >> 13) & 3;
  int c   = (idx >> 15) & 15;
  int l   = idx >> 19;
  int k   = kt * 32 + (lam >> 4) * 8 + j;
  int g   = q * 256 + c * 16 + (lam & 15);
  float v = (k < 256) ? Wih[(l * NG + g) * 256 + k]
                      : Whh[(l * NG + g) * 256 + (k - 256)];
  Wswz[idx] = f2bf(v);
}

__global__ void prep_bias(const float* __restrict__ bih, const float* __restrict__ bhh,
                          float* __restrict__ Bias) {
  int idx = blockIdx.x * 256 + threadIdx.x;        // 51,200 total
  int col = idx & 15; int q = (idx >> 4) & 3; int c = (idx >> 6) & 15; int l = idx >> 10;
  int g = q * 256 + c * 16 + col;
  Bias[idx] = bih[l * NG + g] + bhh[l * NG + g];
}

__global__ void prep_x(const float* __restrict__ x, unsigned short* __restrict__ Xbf) {
  int idx = blockIdx.x * 256 + threadIdx.x;        // 4,194,304 total
  int d = idx & 255; int t = (idx >> 8) & 255; int b = idx >> 16;
  Xbf[(t * NB + b) * 256 + d] = f2bf(x[idx]);
}

__global__ void zero_flags(int* __restrict__ p) {
  p[blockIdx.x * 256 + threadIdx.x] = 0;           // 102,400 ints (prod4+cons4)
}

// ---------------- persistent LSTM kernel ----------------
// Grid 256 (56 exit): x=blockIdx&7 ~ XCD (locality heuristic only; correctness
// never depends on it). ~114KB LDS forces 1 WG/CU -> all 200 workers
// co-resident; each wave's 64KB weight chunk register-resident for all 256 t.
// h exchange: coalesced 16B sc1 loads/stores (LLC coherence point).
// Flags: per-WG stores prod4[l][t][w]=1 (no RMW serialization); consumers
// poll the 4-int vector with one 16B sc1 load. Ordering: producer's h stores
// drain at __syncthreads (vmcnt 0) before the flag store issues; consumer's
// h loads issue only after its poll detects all 4 flags. (Mechanism validated
// by R5/R6 passes; this round only re-encodes the same traffic.)
#define RSTRIDE 81   // LDS row stride in 16B units; 81 % 8 == 1 -> conflict-free
#define HSTRIDE 264  // hout row stride in shorts (16B-aligned rows)
__global__ __launch_bounds__(256, 1) void lstm_persistent(
    const unsigned short* __restrict__ Wswz,
    const float* __restrict__ Bias,
    const unsigned short* __restrict__ Xbf,
    unsigned short* __restrict__ Hring,
    unsigned short* __restrict__ Y,
    int* __restrict__ prod4,
    int* __restrict__ cons4) {
  int xcd = blockIdx.x & 7;
  int jj  = blockIdx.x >> 3;
  int l   = xcd * 7 + (jj >> 2);
  int w   = jj & 3;
  if (jj >= 28 || l >= NL) return;     // 56 idle WGs exit
  int tid = threadIdx.x;

  __shared__ unsigned short hc[64 * RSTRIDE * 8];     // 82,944 B staging
  __shared__ unsigned short hout[64 * HSTRIDE];       // 33,792 B epilogue bounce

  int wv   = tid >> 6;              // wave 0..3
  int ln   = tid & 63;
  int c    = w * 4 + wv;            // gate chunk 0..15 -> hidden units [c*16, c*16+16)
  int colg = ln & 15;
  int quad = ln >> 4;
  bool pvside = (wv & 1);           // staging: odd waves load h_prev half
  int  brb    = wv >> 1;            // staging row-group parity

  // ---- one-time: weights into registers (64 x bf16x8 = 256 VGPRs/lane) ----
  bf16x8 wreg[64];
  {
    const unsigned short* wp = Wswz + (size_t)(l * 16 + c) * 32768 + ln * 8;
#pragma unroll
    for (int i = 0; i < 64; ++i)
      wreg[i] = *(const bf16x8*)(wp + i * 512);
  }
  float bv[4];
  {
    const float* bp = Bias + l * NG + c * 64;
#pragma unroll
    for (int q = 0; q < 4; ++q) bv[q] = bp[q * 16 + colg];
  }

  float cr[4][4] = {};              // cell state in registers
  int j = c * 16 + colg;
  bool last = (l == NL - 1);

  for (int t = 0; t < NT; ++t) {
    // ---- per-wave dependency gate + coalesced staging loads ----
    // Even waves own the In half (k 0..255): gated on prod4[l-1][t][0..3].
    // Odd  waves own the Pv half (k 256..511): gated on prod4[l][t-1][0..3].
    // Per iteration a wave loads 2 half-rows (64 lanes x 16B = 1KB coalesced).
    {
      short8 v[16];
      int e  = ln & 31;             // 16B unit within a 512B half-row
      int rs = ln >> 5;             // row parity within the pair
      if (!pvside) {
        if (l > 0) wave_wait_all4(&prod4[((l - 1) * NT + t) * 4]);
        const unsigned short* In = (l == 0)
            ? (Xbf + t * (NB * 256))
            : (Hring + (((t & 3) * NL + (l - 1)) * NB) * 256);
#pragma unroll
        for (int i = 0; i < 16; ++i) {
          int b = i * 4 + brb * 2 + rs;
          v[i] = ldg_sc1_b128(In + b * 256 + e * 8);
        }
      } else if (t > 0) {
        wave_wait_all4(&prod4[(l * NT + (t - 1)) * 4]);
        const unsigned short* Pv = Hring + ((((t - 1) & 3) * NL + l) * NB) * 256;
#pragma unroll
        for (int i = 0; i < 16; ++i) {
          int b = i * 4 + brb * 2 + rs;
          v[i] = ldg_sc1_b128(Pv + b * 256 + e * 8);
        }
      } else {
#pragma unroll
        for (int i = 0; i < 16; ++i) v[i] = short8{0, 0, 0, 0, 0, 0, 0, 0};
      }
      wait_vm0();                   // all 16 loads landed
      int kb = (pvside ? 32 : 0) + e;
#pragma unroll
      for (int i = 0; i < 16; ++i) {
        int b = i * 4 + brb * 2 + rs;
        *(short8*)(hc + (b * RSTRIDE + kb) * 8) = v[i];
      }
    }
    __syncthreads();
    if (tid == 0 && l > 0)    // upstream slot consumed (loads done before barrier)
      __hip_atomic_store(&cons4[((l - 1) * NT + t) * 4 + w], 1,
                         __ATOMIC_RELAXED, __HIP_MEMORY_SCOPE_AGENT);

    // ---- GEMM: 256 MFMAs/wave, weights from registers ----
    float4v acc[4][4];
#pragma unroll
    for (int q = 0; q < 4; ++q) {
      float4v f4 = {bv[q], bv[q], bv[q], bv[q]};
#pragma unroll
      for (int m = 0; m < 4; ++m) acc[m][q] = f4;
    }
#pragma unroll
    for (int kt = 0; kt < 16; ++kt) {
      bf16x8 a[4];
#pragma unroll
      for (int m = 0; m < 4; ++m)
        a[m] = *(const bf16x8*)(hc + ((m * 16 + colg) * RSTRIDE + kt * 4 + quad) * 8);
#pragma unroll
      for (int m = 0; m < 4; ++m)
#pragma unroll
        for (int q = 0; q < 4; ++q)
          acc[m][q] = __builtin_amdgcn_mfma_f32_16x16x32_bf16(a[m], wreg[q * 16 + kt], acc[m][q], 0, 0, 0);
    }

    // ---- epilogue: gates -> c,h ; scatter h into LDS bounce (own 16 cols) ----
#pragma unroll
    for (int m = 0; m < 4; ++m) {
#pragma unroll
      for (int r = 0; r < 4; ++r) {
        int b = m * 16 + quad * 4 + r;
        float gi = sigmoid_f(acc[m][0][r]);
        float gf = sigmoid_f(acc[m][1][r]);
        float gg = tanh_f(acc[m][2][r]);
        float go = sigmoid_f(acc[m][3][r]);
        float cn = gf * cr[m][r] + gi * gg;   // cr starts 0 => t=0 correct
        cr[m][r] = cn;
        float h = go * tanh_f(cn);
        hout[b * HSTRIDE + j] = f2bf(h);
      }
    }
    // ---- ring backpressure: gates only the flush; usually pre-satisfied.
    if (wv == 0 && !last && t >= 4) wave_wait_all4(&cons4[(l * NT + (t - 4)) * 4]);
    __syncthreads();

    // ---- flush: this WG's 64 columns of each row, coalesced 16B sc1 stores ----
    {
      unsigned short* Hout = Hring + (((t & 3) * NL + l) * NB) * 256;
      unsigned short* Yout = Y + (t * NB) * 256;
#pragma unroll
      for (int pass = 0; pass < 2; ++pass) {
        int u   = pass * 256 + tid;     // 0..511
        int b   = u >> 3;               // row 0..63
        int e8  = u & 7;                // 16B unit within the 128B slice
        int col = w * 64 + e8 * 8;      // shorts
        short8 hv = *(const short8*)(hout + b * HSTRIDE + col);
        stg_sc1_b128(Hout + b * 256 + col, hv);
        if (last) *(short8*)(Yout + b * 256 + col) = hv;
      }
    }
    __syncthreads();                 // vmcnt(0) at barrier => stores at coherence pt
    if (tid == 0)
      __hip_atomic_store(&prod4[(l * NT + t) * 4 + w], 1,
                         __ATOMIC_RELAXED, __HIP_MEMORY_SCOPE_AGENT);
  }
}

// ---------------- final projection ----------------
__global__ void final_proj(const unsigned short* __restrict__ Y,
                           const float* __restrict__ Wout,
                           const float* __restrict__ bout,
                           float* __restrict__ out) {
  int t = blockIdx.x;
  int tid = threadIdx.x;            // 128 = 64 b * 2 o
  int b = tid >> 1, o = tid & 1;
  const unsigned short* yrow = Y + (t * NB + b) * 256;
  const float* wr = Wout + o * 256;
  float s = bout[o];
  for (int k0 = 0; k0 < 256; k0 += 8) {
    short8 yv = *(const short8*)(yrow + k0);
#pragma unroll
    for (int e = 0; e < 8; ++e)
      s += bf2f(((unsigned short*)&yv)[e]) * wr[k0 + e];
  }
  out[(b * NT + t) * 2 + o] = 1.0f / (1.0f + __expf(-s));
}

extern "C" void kernel_launch(void* const* d_in, const int* in_sizes, int n_in,
                              void* d_out, int out_size, void* d_ws, size_t ws_size,
                              hipStream_t stream) {
  (void)in_sizes; (void)n_in; (void)out_size; (void)ws_size;
  const float* x    = (const float*)d_in[0];
  const float* Wih  = (const float*)d_in[1];
  const float* Whh  = (const float*)d_in[2];
  const float* bih  = (const float*)d_in[3];
  const float* bhh  = (const float*)d_in[4];
  const float* Wout = (const float*)d_in[5];
  const float* bout = (const float*)d_in[6];
  float* out = (float*)d_out;

  char* ws = (char*)d_ws;
  unsigned short* Wswz  = (unsigned short*)(ws + OFF_WSWZ);
  float*          Bias  = (float*)(ws + OFF_BIAS);
  unsigned short* Xbf   = (unsigned short*)(ws + OFF_XBF);
  unsigned short* Hring = (unsigned short*)(ws + OFF_HRING);
  unsigned short* Y     = (unsigned short*)(ws + OFF_Y);
  int*            prod4 = (int*)(ws + OFF_PROD);
  int*            cons4 = (int*)(ws + OFF_CONS);

  prep_w    <<<102400, 256, 0, stream>>>(Wih, Whh, Wswz);
  prep_bias <<<200,    256, 0, stream>>>(bih, bhh, Bias);
  prep_x    <<<16384,  256, 0, stream>>>(x, Xbf);
  zero_flags<<<400,    256, 0, stream>>>(prod4);     // prod4+cons4 contiguous

  lstm_persistent<<<256, 256, 0, stream>>>(Wswz, Bias, Xbf, Hring, Y, prod4, cons4);

  final_proj<<<NT, 128, 0, stream>>>(Y, Wout, bout, out);
}

// Round 2
// 2005.882 us; speedup vs baseline: 1.2132x; 1.2132x over previous
//
#include <hip/hip_runtime.h>
#include <hip/hip_bf16.h>
#include <stdint.h>
#include <string.h>

// ---------------- problem constants ----------------
// B=64, T=256, D=H=256, L=50, O=2; K = 2H = 512 (concat [h_in; h_prev]); G = 4H = 1024
#define NB   64
#define NT   256
#define NH   256
#define NL   50
#define NK   512
#define NG   1024

typedef __attribute__((ext_vector_type(8)))  short   short8;
typedef __attribute__((ext_vector_type(8)))  __bf16  bf16x8;
typedef __attribute__((ext_vector_type(4)))  float   float4v;
typedef __attribute__((ext_vector_type(4)))  int     int4v;

#define LOG2E_F    1.44269504088896340736f
#define TWOLOG2E_F 2.88539008177792681472f

__device__ __forceinline__ unsigned short f2bf(float f) {
  union { float f; uint32_t u; } v; v.f = f;
  uint32_t u = v.u;
  uint32_t r = (u + 0x7FFFu + ((u >> 16) & 1u)) >> 16;   // RNE
  return (unsigned short)r;
}
__device__ __forceinline__ float bf2f(unsigned short s) {
  union { uint32_t u; float f; } v; v.u = ((uint32_t)s) << 16;
  return v.f;
}
// Division-free activations on PRE-SCALED gates (weights/bias folded with
// log2e for i,f,o and 2*log2e for g at prep time).
//   sig2(x')  = 1/(1+2^-x')        == sigmoid(x)  for x' = x*log2e
//   th2(x'')  = 2/(1+2^-x'') - 1   == tanh(x)     for x'' = x*2*log2e
// Overflow-safe: exp2(+inf)->inf -> rcp->0; exp2(-inf)->0. No NaNs.
__device__ __forceinline__ float sig2(float x) {
  float e = __builtin_amdgcn_exp2f(-x);
  return __builtin_amdgcn_rcpf(1.0f + e);
}
__device__ __forceinline__ float th2(float x) {
  float e = __builtin_amdgcn_exp2f(-x);
  return __builtin_fmaf(2.0f, __builtin_amdgcn_rcpf(1.0f + e), -1.0f);
}

// ---- coherent, COALESCED 16B ops (sc1 = agent scope, LLC-direct) ----
__device__ __forceinline__ short8 ldg_sc1_b128(const unsigned short* p) {
  short8 r;
  asm volatile("global_load_dwordx4 %0, %1, off sc1" : "=v"(r) : "v"(p) : "memory");
  return r;
}
__device__ __forceinline__ void stg_sc1_b128(unsigned short* p, short8 v) {
  asm volatile("global_store_dwordx4 %0, %1, off sc1" :: "v"(p), "v"(v) : "memory");
}
__device__ __forceinline__ void wait_vm0() {
  asm volatile("s_waitcnt vmcnt(0)" ::: "memory");
}
// poll 4 per-WG flags with ONE 16B coherent load (all lanes same addr -> 1 txn)
__device__ __forceinline__ void wave_wait_all4(const int* p) {
  for (;;) {
    int4v f;
    asm volatile("global_load_dwordx4 %0, %1, off sc1\n\ts_waitcnt vmcnt(0)"
                 : "=v"(f) : "v"(p) : "memory");
    if ((f[0] & f[1] & f[2] & f[3]) != 0) break;
  }
}

// ---------------- workspace layout (bytes) ----------------
#define OFF_WSWZ  0
#define OFF_BIAS  52428800
#define OFF_XBF   52633600
#define OFF_HRING 61022208
#define OFF_Y     67575808
#define OFF_PROD  75964416
#define OFF_CONS  76169216
// total: 76,374,016 bytes  (prod4/cons4: 50*256*4 ints = 204,800 B each)

// ---------------- preprocessing ----------------
// Weight swizzle: Wswz[idx], idx = ((((l*16+c)*4+q)*16+kt)*64+lam)*8+j
// holds Wcat[g = q*256 + c*16 + (lam&15)][k = kt*32 + (lam>>4)*8 + j] as bf16,
// PRE-SCALED by log2e (gates i,f,o) or 2*log2e (gate g) so the epilogue can
// use exp2-based division-free activations.
__global__ void prep_w(const float* __restrict__ Wih, const float* __restrict__ Whh,
                       unsigned short* __restrict__ Wswz) {
  int idx = blockIdx.x * 256 + threadIdx.x;        // 26,214,400 total
  int j   = idx & 7;
  int lam = (idx >> 3) & 63;
  int kt  = (idx >> 9) & 15;
  int q   = (idx >> 13) & 3;
  int c   = (idx >> 15) & 15;
  int l   = idx >> 19;
  int k   = kt * 32 + (lam >> 4) * 8 + j;
  int g   = q * 256 + c * 16 + (lam & 15);
  float v = (k < 256) ? Wih[(l * NG + g) * 256 + k]
                      : Whh[(l * NG + g) * 256 + (k - 256)];
  v *= (q == 2) ? TWOLOG2E_F : LOG2E_F;            // gate order i,f,g,o
  Wswz[idx] = f2bf(v);
}

__global__ void prep_bias(const float* __restrict__ bih, const float* __restrict__ bhh,
                          float* __restrict__ Bias) {
  int idx = blockIdx.x * 256 + threadIdx.x;        // 51,200 total
  int col = idx & 15; int q = (idx >> 4) & 3; int c = (idx >> 6) & 15; int l = idx >> 10;
  int g = q * 256 + c * 16 + col;
  float v = bih[l * NG + g] + bhh[l * NG + g];
  v *= (q == 2) ? TWOLOG2E_F : LOG2E_F;
  Bias[idx] = v;
}

__global__ void prep_x(const float* __restrict__ x, unsigned short* __restrict__ Xbf) {
  int idx = blockIdx.x * 256 + threadIdx.x;        // 4,194,304 total
  int d = idx & 255; int t = (idx >> 8) & 255; int b = idx >> 16;
  Xbf[(t * NB + b) * 256 + d] = f2bf(x[idx]);
}

__global__ void zero_flags(int* __restrict__ p) {
  p[blockIdx.x * 256 + threadIdx.x] = 0;           // 102,400 ints (prod4+cons4)
}

// ---------------- persistent LSTM kernel ----------------
// Grid 256 (56 exit). ~114KB LDS forces 1 WG/CU. Weights register-resident.
// h exchange: coalesced 16B sc1 loads/stores (LLC coherence point).
// Per-step barriers: A (staging complete), B (hout complete / ring gate).
// The old 3rd barrier is replaced by per-wave store-drain + LDS counter;
// the 4th (last-draining) wave publishes prod4. Safety: any wave staging
// step t+1 has passed barrier B(t) (so all hc(t) MFMA reads are done), and
// odd-wave polls of prod4[l][t] require all 4 own waves drained.
#define RSTRIDE 81   // LDS row stride in 16B units; 81 % 8 == 1 -> conflict-free
#define HSTRIDE 264  // hout row stride in shorts (16B-aligned rows)
__global__ __launch_bounds__(256, 1) void lstm_persistent(
    const unsigned short* __restrict__ Wswz,
    const float* __restrict__ Bias,
    const unsigned short* __restrict__ Xbf,
    unsigned short* __restrict__ Hring,
    unsigned short* __restrict__ Y,
    int* __restrict__ prod4,
    int* __restrict__ cons4) {
  int xcd = blockIdx.x & 7;
  int jj  = blockIdx.x >> 3;
  int l   = xcd * 7 + (jj >> 2);
  int w   = jj & 3;
  if (jj >= 28 || l >= NL) return;     // 56 idle WGs exit
  int tid = threadIdx.x;

  __shared__ unsigned short hc[64 * RSTRIDE * 8];     // 82,944 B staging
  __shared__ unsigned short hout[64 * HSTRIDE];       // 33,792 B epilogue bounce
  __shared__ int cnt_fl;                              // flush-drain counter

  int wv   = tid >> 6;              // wave 0..3
  int ln   = tid & 63;
  int c    = w * 4 + wv;            // gate chunk 0..15 -> hidden units [c*16, c*16+16)
  int colg = ln & 15;
  int quad = ln >> 4;
  bool pvside = (wv & 1);           // staging: odd waves load h_prev half
  int  brb    = wv >> 1;            // staging row-group parity

  if (tid == 0) cnt_fl = 0;         // published by t=0 staging barrier

  // ---- one-time: weights into registers (64 x bf16x8 = 256 VGPRs/lane) ----
  bf16x8 wreg[64];
  {
    const unsigned short* wp = Wswz + (size_t)(l * 16 + c) * 32768 + ln * 8;
#pragma unroll
    for (int i = 0; i < 64; ++i)
      wreg[i] = *(const bf16x8*)(wp + i * 512);
  }
  float bv[4];
  {
    const float* bp = Bias + l * NG + c * 64;
#pragma unroll
    for (int q = 0; q < 4; ++q) bv[q] = bp[q * 16 + colg];
  }

  float cr[4][4] = {};              // cell state in registers
  int j = c * 16 + colg;
  bool last = (l == NL - 1);

  for (int t = 0; t < NT; ++t) {
    // ---- per-wave dependency gate + coalesced staging loads ----
    {
      short8 v[16];
      int e  = ln & 31;             // 16B unit within a 512B half-row
      int rs = ln >> 5;             // row parity within the pair
      if (!pvside) {
        if (l > 0) wave_wait_all4(&prod4[((l - 1) * NT + t) * 4]);
        const unsigned short* In = (l == 0)
            ? (Xbf + t * (NB * 256))
            : (Hring + (((t & 3) * NL + (l - 1)) * NB) * 256);
#pragma unroll
        for (int i = 0; i < 16; ++i) {
          int b = i * 4 + brb * 2 + rs;
          v[i] = ldg_sc1_b128(In + b * 256 + e * 8);
        }
      } else if (t > 0) {
        wave_wait_all4(&prod4[(l * NT + (t - 1)) * 4]);
        const unsigned short* Pv = Hring + ((((t - 1) & 3) * NL + l) * NB) * 256;
#pragma unroll
        for (int i = 0; i < 16; ++i) {
          int b = i * 4 + brb * 2 + rs;
          v[i] = ldg_sc1_b128(Pv + b * 256 + e * 8);
        }
      } else {
#pragma unroll
        for (int i = 0; i < 16; ++i) v[i] = short8{0, 0, 0, 0, 0, 0, 0, 0};
      }
      wait_vm0();                   // all 16 loads landed
      int kb = (pvside ? 32 : 0) + e;
#pragma unroll
      for (int i = 0; i < 16; ++i) {
        int b = i * 4 + brb * 2 + rs;
        *(short8*)(hc + (b * RSTRIDE + kb) * 8) = v[i];
      }
    }
    __syncthreads();                // barrier A: staging complete
    if (tid == 0 && l > 0)          // upstream slot consumed
      __hip_atomic_store(&cons4[((l - 1) * NT + t) * 4 + w], 1,
                         __ATOMIC_RELAXED, __HIP_MEMORY_SCOPE_AGENT);

    // ---- GEMM: 256 MFMAs/wave, weights from registers ----
    float4v acc[4][4];
#pragma unroll
    for (int q = 0; q < 4; ++q) {
      float4v f4 = {bv[q], bv[q], bv[q], bv[q]};
#pragma unroll
      for (int m = 0; m < 4; ++m) acc[m][q] = f4;
    }
#pragma unroll
    for (int kt = 0; kt < 16; ++kt) {
      bf16x8 a[4];
#pragma unroll
      for (int m = 0; m < 4; ++m)
        a[m] = *(const bf16x8*)(hc + ((m * 16 + colg) * RSTRIDE + kt * 4 + quad) * 8);
#pragma unroll
      for (int m = 0; m < 4; ++m)
#pragma unroll
        for (int q = 0; q < 4; ++q)
          acc[m][q] = __builtin_amdgcn_mfma_f32_16x16x32_bf16(a[m], wreg[q * 16 + kt], acc[m][q], 0, 0, 0);
    }

    // ---- epilogue: division-free gates -> c,h ; pk-pack h into LDS bounce ----
#pragma unroll
    for (int m = 0; m < 4; ++m) {
      float hv[4];
#pragma unroll
      for (int r = 0; r < 4; ++r) {
        float gi = sig2(acc[m][0][r]);
        float gf = sig2(acc[m][1][r]);
        float gg = th2(acc[m][2][r]);
        float go = sig2(acc[m][3][r]);
        float cn = gf * cr[m][r] + gi * gg;   // cr starts 0 => t=0 correct
        cr[m][r] = cn;
        hv[r] = go * th2(cn * TWOLOG2E_F);
      }
      uint32_t pk01, pk23;
      asm("v_cvt_pk_bf16_f32 %0, %1, %2" : "=v"(pk01) : "v"(hv[0]), "v"(hv[1]));
      asm("v_cvt_pk_bf16_f32 %0, %1, %2" : "=v"(pk23) : "v"(hv[2]), "v"(hv[3]));
      unsigned short* hp = hout + (m * 16 + quad * 4) * HSTRIDE + j;
      hp[0]           = (unsigned short)pk01;
      hp[HSTRIDE]     = (unsigned short)(pk01 >> 16);
      hp[2 * HSTRIDE] = (unsigned short)pk23;
      hp[3 * HSTRIDE] = (unsigned short)(pk23 >> 16);
    }
    // ---- ring backpressure: gates only the flush; usually pre-satisfied.
    if (wv == 0 && !last && t >= 4) wave_wait_all4(&cons4[(l * NT + (t - 4)) * 4]);
    __syncthreads();                // barrier B: hout complete + ring gate

    // ---- flush: this WG's 64 columns of each row, coalesced 16B sc1 stores ----
    {
      unsigned short* Hout = Hring + (((t & 3) * NL + l) * NB) * 256;
      unsigned short* Yout = Y + (t * NB) * 256;
#pragma unroll
      for (int pass = 0; pass < 2; ++pass) {
        int u   = pass * 256 + tid;     // 0..511
        int b   = u >> 3;               // row 0..63
        int e8  = u & 7;                // 16B unit within the 128B slice
        int col = w * 64 + e8 * 8;      // shorts
        short8 hv = *(const short8*)(hout + b * HSTRIDE + col);
        stg_sc1_b128(Hout + b * 256 + col, hv);
        if (last) *(short8*)(Yout + b * 256 + col) = hv;
      }
    }
    // ---- per-wave drain + counter; 4th wave publishes the flag (no barrier) ----
    wait_vm0();                     // this wave's h stores at coherence point
    if (ln == 0) {
      int old = atomicAdd(&cnt_fl, 1);
      if (old == 4 * t + 3)
        __hip_atomic_store(&prod4[(l * NT + t) * 4 + w], 1,
                           __ATOMIC_RELAXED, __HIP_MEMORY_SCOPE_AGENT);
    }
  }
}

// ---------------- final projection ----------------
__global__ void final_proj(const unsigned short* __restrict__ Y,
                           const float* __restrict__ Wout,
                           const float* __restrict__ bout,
                           float* __restrict__ out) {
  int t = blockIdx.x;
  int tid = threadIdx.x;            // 128 = 64 b * 2 o
  int b = tid >> 1, o = tid & 1;
  const unsigned short* yrow = Y + (t * NB + b) * 256;
  const float* wr = Wout + o * 256;
  float s = bout[o];
  for (int k0 = 0; k0 < 256; k0 += 8) {
    short8 yv = *(const short8*)(yrow + k0);
#pragma unroll
    for (int e = 0; e < 8; ++e)
      s += bf2f(((unsigned short*)&yv)[e]) * wr[k0 + e];
  }
  out[(b * NT + t) * 2 + o] = 1.0f / (1.0f + __expf(-s));
}

extern "C" void kernel_launch(void* const* d_in, const int* in_sizes, int n_in,
                              void* d_out, int out_size, void* d_ws, size_t ws_size,
                              hipStream_t stream) {
  (void)in_sizes; (void)n_in; (void)out_size; (void)ws_size;
  const float* x    = (const float*)d_in[0];
  const float* Wih  = (const float*)d_in[1];
  const float* Whh  = (const float*)d_in[2];
  const float* bih  = (const float*)d_in[3];
  const float* bhh  = (const float*)d_in[4];
  const float* Wout = (const float*)d_in[5];
  const float* bout = (const float*)d_in[6];
  float* out = (float*)d_out;

  char* ws = (char*)d_ws;
  unsigned short* Wswz  = (unsigned short*)(ws + OFF_WSWZ);
  float*          Bias  = (float*)(ws + OFF_BIAS);
  unsigned short* Xbf   = (unsigned short*)(ws + OFF_XBF);
  unsigned short* Hring = (unsigned short*)(ws + OFF_HRING);
  unsigned short* Y     = (unsigned short*)(ws + OFF_Y);
  int*            prod4 = (int*)(ws + OFF_PROD);
  int*            cons4 = (int*)(ws + OFF_CONS);

  prep_w    <<<102400, 256, 0, stream>>>(Wih, Whh, Wswz);
  prep_bias <<<200,    256, 0, stream>>>(bih, bhh, Bias);
  prep_x    <<<16384,  256, 0, stream>>>(x, Xbf);
  zero_flags<<<400,    256, 0, stream>>>(prod4);     // prod4+cons4 contiguous

  lstm_persistent<<<256, 256, 0, stream>>>(Wswz, Bias, Xbf, Hring, Y, prod4, cons4);

  final_proj<<<NT, 128, 0, stream>>>(Y, Wout, bout, out);
}